// Round 10
// baseline (1108.121 us; speedup 1.0000x reference)
//
#include <hip/hip_runtime.h>
#include <math.h>

// Problem constants (from reference)
#define BG    100        // graphs
#define NPG   500        // nodes per graph (layer 1)
#define FD    128        // feature dim (F_IN == H == 128)
#define EE    600000     // edges
#define EPG   6000       // edges per graph (contiguous, never cross graphs)
#define NN    50000      // total nodes layer 1
#define K1    250
#define K2    125
#define K3    63
#define CAP   64         // max in-degree capacity
#define GRIDN (2 * BG)   // tail_chain grid (co-resident: 48KB LDS, 16 waves -> >=1 blk/CU)

typedef short v8s __attribute__((ext_vector_type(8)));
typedef float v4f __attribute__((ext_vector_type(4)));

// XCD-aligned swizzle (R9 win)
__device__ __forceinline__ int swz(int p, int N) {
    int j = p & 7, i = p >> 3;
    int chunk = N >> 3, rem = N & 7;
    int mj = j < rem ? j : rem;
    return j * chunk + mj + i;
}

// float -> bf16 RNE bits
__device__ __forceinline__ unsigned short f2bf(float f) {
    unsigned int u = __float_as_uint(f);
    unsigned int r = (u + 0x7FFFu + ((u >> 16) & 1u)) >> 16;
    return (unsigned short)r;
}
__device__ __forceinline__ float bf2f(unsigned short b) {
    return __uint_as_float(((unsigned int)b) << 16);
}

// ---- software grid barrier (agent-scope; co-residency guaranteed by geometry) ----
__device__ __forceinline__ void grid_sync(unsigned* bar, unsigned nb) {
    __threadfence();                 // release: flush this block's writes to coherence point
    __syncthreads();
    if (threadIdx.x == 0) {
        unsigned old = __hip_atomic_fetch_add(bar, 1u, __ATOMIC_ACQ_REL, __HIP_MEMORY_SCOPE_AGENT);
        unsigned target = (old / nb + 1u) * nb;
        while (__hip_atomic_load(bar, __ATOMIC_ACQUIRE, __HIP_MEMORY_SCOPE_AGENT) < target)
            __builtin_amdgcn_s_sleep(8);
    }
    __syncthreads();
    __threadfence();                 // acquire: invalidate stale cache lines
}

// ---------------- merged prep: blocks [0,BG) build layer-1 CSR (LDS counters);
// blocks [BG, BG+96) convert W -> Wt_hi/Wt_lo bf16 in MFMA-staging order:
// o = [layer][kt=k>>5][t=n>>4][quad=(k>>3)&3][l15=n&15][q=k&7]  (k = [Wl | Wr] rows)
__global__ __launch_bounds__(1024) void prep_fill_kernel(
        const int* __restrict__ ei, int* __restrict__ deg, int* __restrict__ col,
        const float* __restrict__ Wl1, const float* __restrict__ Wr1,
        const float* __restrict__ Wl2, const float* __restrict__ Wr2,
        const float* __restrict__ Wl3, const float* __restrict__ Wr3,
        unsigned short* __restrict__ wt_hi, unsigned short* __restrict__ wt_lo,
        unsigned* __restrict__ bar) {
    __shared__ int lcnt[NPG];
    int tid = threadIdx.x;
    if (blockIdx.x == BG && tid == 0) *bar = 0u;   // reset grid barrier each launch/replay
    if (blockIdx.x < BG) {
        int b = swz(blockIdx.x, BG);
        for (int i = tid; i < NPG; i += 1024) lcnt[i] = 0;
        __syncthreads();
        for (int e0 = tid; e0 < EPG; e0 += 1024) {
            int e = b * EPG + e0;
            int d = ei[EE + e];
            int pos = atomicAdd(&lcnt[d - b * NPG], 1);
            if (pos < CAP) col[(long long)d * CAP + pos] = ei[e];
        }
        __syncthreads();
        for (int i = tid; i < NPG; i += 1024) deg[b * NPG + i] = lcnt[i];
    } else {
        int id = (blockIdx.x - BG) * 1024 + tid;          // 3*256*128 = 98304
        if (id >= 3 * 256 * 128) return;
        int layer = id >> 15, rem = id & 32767;
        int k = rem >> 7, n = rem & 127;
        const float* Wl = layer == 0 ? Wl1 : (layer == 1 ? Wl2 : Wl3);
        const float* Wr = layer == 0 ? Wr1 : (layer == 1 ? Wr2 : Wr3);
        float w = (k < 128) ? Wl[k * 128 + n] : Wr[(k - 128) * 128 + n];
        unsigned short hi = f2bf(w);
        unsigned short lo = f2bf(w - bf2f(hi));
        long long o = (long long)layer * 32768
                    + (long long)(k >> 5) * 4096          // kt
                    + (long long)(n >> 4) * 512           // t
                    + (long long)((k >> 3) & 3) * 128     // quad
                    + (long long)(n & 15) * 8             // l15
                    + (k & 7);                            // q
        wt_hi[o] = hi;
        wt_lo[o] = lo;
    }
}

// ---------------- gather-aggregate layer 1 (coalesced, high TLP, 8-way pipelined) ----
__global__ void gather_agg_kernel(const int* __restrict__ deg, const int* __restrict__ col,
                                  const float* __restrict__ x, float* __restrict__ mean,
                                  int n, int NB) {
    int g = swz(blockIdx.x, NB) * 256 + threadIdx.x;
    int node = g >> 5, sub = g & 31;
    if (node >= n) return;
    int d = deg[node]; if (d > CAP) d = CAP;
    const int* cp = col + (long long)node * CAP;
    float ax = 0.0f, ay = 0.0f, az = 0.0f, aw = 0.0f;
    int j = 0;
    for (; j + 8 <= d; j += 8) {
        float4 v0 = ((const float4*)(x + (long long)cp[j]     * FD))[sub];
        float4 v1 = ((const float4*)(x + (long long)cp[j + 1] * FD))[sub];
        float4 v2 = ((const float4*)(x + (long long)cp[j + 2] * FD))[sub];
        float4 v3 = ((const float4*)(x + (long long)cp[j + 3] * FD))[sub];
        float4 v4 = ((const float4*)(x + (long long)cp[j + 4] * FD))[sub];
        float4 v5 = ((const float4*)(x + (long long)cp[j + 5] * FD))[sub];
        float4 v6 = ((const float4*)(x + (long long)cp[j + 6] * FD))[sub];
        float4 v7 = ((const float4*)(x + (long long)cp[j + 7] * FD))[sub];
        ax += v0.x; ay += v0.y; az += v0.z; aw += v0.w;
        ax += v1.x; ay += v1.y; az += v1.z; aw += v1.w;
        ax += v2.x; ay += v2.y; az += v2.z; aw += v2.w;
        ax += v3.x; ay += v3.y; az += v3.z; aw += v3.w;
        ax += v4.x; ay += v4.y; az += v4.z; aw += v4.w;
        ax += v5.x; ay += v5.y; az += v5.z; aw += v5.w;
        ax += v6.x; ay += v6.y; az += v6.z; aw += v6.w;
        ax += v7.x; ay += v7.y; az += v7.z; aw += v7.w;
    }
    for (; j + 4 <= d; j += 4) {
        float4 v0 = ((const float4*)(x + (long long)cp[j]     * FD))[sub];
        float4 v1 = ((const float4*)(x + (long long)cp[j + 1] * FD))[sub];
        float4 v2 = ((const float4*)(x + (long long)cp[j + 2] * FD))[sub];
        float4 v3 = ((const float4*)(x + (long long)cp[j + 3] * FD))[sub];
        ax += v0.x; ay += v0.y; az += v0.z; aw += v0.w;
        ax += v1.x; ay += v1.y; az += v1.z; aw += v1.w;
        ax += v2.x; ay += v2.y; az += v2.z; aw += v2.w;
        ax += v3.x; ay += v3.y; az += v3.z; aw += v3.w;
    }
    for (; j < d; ++j) {
        float4 v = ((const float4*)(x + (long long)cp[j] * FD))[sub];
        ax += v.x; ay += v.y; az += v.z; aw += v.w;
    }
    float inv = 1.0f / fmaxf((float)d, 1.0f);
    float4 o; o.x = ax * inv; o.y = ay * inv; o.z = az * inv; o.w = aw * inv;
    ((float4*)(mean + (long long)node * FD))[sub] = o;
}

// ---------------- SAGE GEMM layer 1 (R9: 128-row tile, 8 waves, dbuf B staging) -------
__global__ __launch_bounds__(512) void sage_gemm_mfma_kernel(
        const float* __restrict__ mean, const float* __restrict__ x,
        const unsigned short* __restrict__ wt_hi, const unsigned short* __restrict__ wt_lo,
        const float* __restrict__ bl, const float* __restrict__ pw,
        float* __restrict__ hout, float* __restrict__ score, int M, int NB) {
    __shared__ unsigned short Bh[2][4096], Bl[2][4096];
    __shared__ float spart[128 * 16];
    __shared__ float snrmp[16];
    int tid  = threadIdx.x;
    int wave = tid >> 6, lane = tid & 63;
    int quad = lane >> 4, l15 = lane & 15;
    int row0 = swz(blockIdx.x, NB) * 128;

    v4f acc[8];
#pragma unroll
    for (int t = 0; t < 8; t++) acc[t] = (v4f){0.f, 0.f, 0.f, 0.f};

    if (tid < 16) {
        float s = 0.f;
#pragma unroll
        for (int t = 0; t < 8; t++) { float p = pw[t * 16 + tid]; s += p * p; }
        snrmp[tid] = s;
    }

    int growA = row0 + 16 * wave + l15; if (growA > M - 1) growA = M - 1;

    uint4 gh = ((const uint4*)(wt_hi))[tid];
    uint4 gl = ((const uint4*)(wt_lo))[tid];
    const float* ap0 = mean + (long long)growA * FD + quad * 8;
    float4 av0 = *(const float4*)(ap0);
    float4 av1 = *(const float4*)(ap0 + 4);
    *(uint4*)&Bh[0][tid * 8] = gh;
    *(uint4*)&Bl[0][tid * 8] = gl;

    for (int kt = 0; kt < 8; ++kt) {
        int cur = kt & 1;
        float f[8] = {av0.x, av0.y, av0.z, av0.w, av1.x, av1.y, av1.z, av1.w};
        v8s a_h, a_l;
#pragma unroll
        for (int q = 0; q < 8; q++) {
            unsigned short hb = f2bf(f[q]);
            a_h[q] = (short)hb;
            a_l[q] = (short)f2bf(f[q] - bf2f(hb));
        }
        if (kt < 7) {
            gh = ((const uint4*)(wt_hi + (kt + 1) * 4096))[tid];
            gl = ((const uint4*)(wt_lo + (kt + 1) * 4096))[tid];
            const float* Ab = (kt + 1 < 4) ? mean : x;
            const float* apn = Ab + (long long)growA * FD
                             + ((kt + 1 < 4) ? (kt + 1) : (kt - 3)) * 32 + quad * 8;
            av0 = *(const float4*)(apn);
            av1 = *(const float4*)(apn + 4);
        }
        __syncthreads();
#pragma unroll
        for (int t = 0; t < 8; t++) {
            v8s b_h = *(const v8s*)&Bh[cur][t * 512 + lane * 8];
            v8s b_l = *(const v8s*)&Bl[cur][t * 512 + lane * 8];
            acc[t] = __builtin_amdgcn_mfma_f32_16x16x32_bf16(a_l, b_h, acc[t], 0, 0, 0);
            acc[t] = __builtin_amdgcn_mfma_f32_16x16x32_bf16(a_h, b_l, acc[t], 0, 0, 0);
            acc[t] = __builtin_amdgcn_mfma_f32_16x16x32_bf16(a_h, b_h, acc[t], 0, 0, 0);
        }
        if (kt < 7) {
            *(uint4*)&Bh[cur ^ 1][tid * 8] = gh;
            *(uint4*)&Bl[cur ^ 1][tid * 8] = gl;
        }
    }

    int rbase = row0 + 16 * wave + quad * 4;
    float part[4] = {0.f, 0.f, 0.f, 0.f};
#pragma unroll
    for (int t = 0; t < 8; t++) {
        int colc = t * 16 + l15;
        float blv = bl[colc];
        float pwv = pw[colc];
#pragma unroll
        for (int reg = 0; reg < 4; reg++) {
            float h = fmaxf(acc[t][reg] + blv, 0.0f);
            part[reg] += h * pwv;
            int grow = rbase + reg;
            if (grow < M) hout[(long long)grow * FD + colc] = h;
        }
    }
#pragma unroll
    for (int reg = 0; reg < 4; reg++)
        spart[(16 * wave + quad * 4 + reg) * 16 + l15] = part[reg];
    __syncthreads();
    if (tid < 128) {
        int grow = row0 + tid;
        if (grow < M) {
            float dot = 0.0f;
#pragma unroll
            for (int i = 0; i < 16; i++) dot += spart[tid * 16 + i];
            float nr = 0.0f;
#pragma unroll
            for (int i = 0; i < 16; i++) nr += snrmp[i];
            score[grow] = tanhf(dot / sqrtf(nr));
        }
    }
}

// ================= tail chain: single kernel, full-width phases, grid barriers ========
struct TailSM {
    float skey[512]; int sidx[512];
    unsigned long long spk[512];
    int lmap[512]; int lcnt[512];
    float pmax[1024]; float psum[1024];
    float zs[256], t1[128], t2[64], t3[16];
};
struct GemmSM {
    unsigned short Bh[2][4096], Bl[2][4096];
    float spart[256 * 16];
    float snrmp[16];
};
union ChainSM { TailSM t; GemmSM g; };

// ---- tail phase (verbatim R9 topk_tail body; returns replaced by structured ifs) ----
__device__ void tail_phase(ChainSM* sm,
        const float* score, const float* hout,
        int n_per, int k, int SN, float* xp,
        const int* esrc, const int* edst, int* gmap,
        int* next_deg, int* next_col, float* z, int mode,
        const float* W1, const float* b1, const float* W2, const float* b2,
        const float* W3, const float* b3, float* out) {
    TailSM* t = &sm->t;
    int tid = threadIdx.x;
    int kind, b;
    bool active = true;
    if (mode == 2) {
        kind = 1;
        if ((int)blockIdx.x >= BG) active = false;
        b = swz(active ? blockIdx.x : 0, BG);
    } else {
        kind = blockIdx.x >= BG ? 1 : 0;
        b = swz(kind ? blockIdx.x - BG : blockIdx.x, BG);
    }
    if (!active) return;   // per-block uniform; skipped blocks rejoin at grid_sync

    if (kind == 0)
        for (int i = tid; i < SN; i += 1024) { t->lmap[i] = -1; t->lcnt[i] = 0; }

    // ---- register bitonic sort on packed keys (desc key, asc idx) ----
    unsigned long long P = 0ULL;
    if (tid < SN) {
        float keyv; unsigned int idx;
        if (tid < n_per) { keyv = score[b * n_per + tid]; idx = (unsigned int)tid; }
        else             { keyv = -INFINITY;              idx = 0x7fffffffu; }
        unsigned int u = __float_as_uint(keyv);
        u = (u & 0x80000000u) ? ~u : (u | 0x80000000u);
        P = ((unsigned long long)u << 32) | (unsigned long long)(~idx);
    }
    for (int ks = 2; ks <= SN; ks <<= 1) {
        for (int j = ks >> 1; j > 0; j >>= 1) {
            unsigned long long Q;
            if (j >= 64) {
                __syncthreads();
                if (tid < SN) t->spk[tid] = P;
                __syncthreads();
                Q = (tid < SN) ? t->spk[tid ^ j] : 0ULL;
            } else {
                Q = __shfl_xor(P, j, 64);
            }
            if (tid < SN) {
                bool keepmax = (((tid & ks) == 0) == ((tid & j) == 0));
                if (keepmax == (Q > P)) P = Q;
            }
        }
    }
    if (tid < SN) {
        unsigned int u  = (unsigned int)(P >> 32);
        unsigned int fb = (u & 0x80000000u) ? (u & 0x7fffffffu) : ~u;
        int iv = (int)(~(unsigned int)P);
        t->skey[tid] = __uint_as_float(fb);
        t->sidx[tid] = iv;
        if (kind == 0 && tid < k) t->lmap[iv] = tid;
    }
    __syncthreads();

    if (kind == 0) {
        int kbase = b * k;
        if (mode == 0) {
            int nbase = b * n_per;
            for (int e0 = tid; e0 < EPG; e0 += 1024) {
                int e = b * EPG + e0;
                int ls = t->lmap[esrc[e] - nbase];
                int ld = t->lmap[edst[e] - nbase];
                if (ls >= 0 && ld >= 0) {
                    int pos = atomicAdd(&t->lcnt[ld], 1);
                    if (pos < CAP) next_col[(long long)(kbase + ld) * CAP + pos] = kbase + ls;
                }
            }
            __syncthreads();
            for (int i = tid; i < NPG; i += 1024) {
                int l = t->lmap[i];
                gmap[nbase + i] = l >= 0 ? kbase + l : -1;
            }
        } else {
            int kb1 = b * n_per;
            int nbase0 = b * NPG;
            for (int e0 = tid; e0 < EPG; e0 += 1024) {
                int e = b * EPG + e0;
                int ws = gmap[esrc[e]];
                int wd = gmap[edst[e]];
                (void)nbase0;
                int ls = (ws >= 0) ? t->lmap[ws - kb1] : -1;
                int ld = (wd >= 0) ? t->lmap[wd - kb1] : -1;
                if (ls >= 0 && ld >= 0) {
                    int pos = atomicAdd(&t->lcnt[ld], 1);
                    if (pos < CAP) next_col[(long long)(kbase + ld) * CAP + pos] = kbase + ls;
                }
            }
            __syncthreads();
        }
        for (int i = tid; i < k; i += 1024) next_deg[kbase + i] = t->lcnt[i];
        return;   // kind0 done; rejoins at grid_sync
    }

    // ---- kind 1: pool -> xp, readout ----
    int c = tid & 127, s = tid >> 7;
    float mx = -INFINITY, sm2 = 0.0f;
    {
        int r = s;
        long long hbase = (long long)b * n_per * FD + c;
        long long xbase = (long long)b * k * FD + c;
        for (; r + 24 < k; r += 32) {
            int i0 = t->sidx[r], i1 = t->sidx[r + 8], i2 = t->sidx[r + 16], i3 = t->sidx[r + 24];
            float k0 = t->skey[r], k1 = t->skey[r + 8], k2 = t->skey[r + 16], k3 = t->skey[r + 24];
            float v0 = hout[hbase + (long long)i0 * FD] * k0;
            float v1 = hout[hbase + (long long)i1 * FD] * k1;
            float v2 = hout[hbase + (long long)i2 * FD] * k2;
            float v3 = hout[hbase + (long long)i3 * FD] * k3;
            if (mode != 2) {
                xp[xbase + (long long)(r)      * FD] = v0;
                xp[xbase + (long long)(r + 8)  * FD] = v1;
                xp[xbase + (long long)(r + 16) * FD] = v2;
                xp[xbase + (long long)(r + 24) * FD] = v3;
            }
            mx = fmaxf(mx, v0); sm2 += v0;
            mx = fmaxf(mx, v1); sm2 += v1;
            mx = fmaxf(mx, v2); sm2 += v2;
            mx = fmaxf(mx, v3); sm2 += v3;
        }
        for (; r < k; r += 8) {
            float v = hout[hbase + (long long)t->sidx[r] * FD] * t->skey[r];
            if (mode != 2) xp[xbase + (long long)r * FD] = v;
            mx = fmaxf(mx, v); sm2 += v;
        }
    }
    t->pmax[tid] = mx; t->psum[tid] = sm2;
    __syncthreads();
    if (tid < 128) {
        float m = -INFINITY, su = 0.0f;
#pragma unroll
        for (int i = 0; i < 8; i++) {
            m = fmaxf(m, t->pmax[i * 128 + tid]);
            su += t->psum[i * 128 + tid];
        }
        float mean = su / (float)k;
        if (mode == 0)      { z[b * 256 + tid] = m;  z[b * 256 + 128 + tid] = mean;  }
        else if (mode == 1) { z[b * 256 + tid] += m; z[b * 256 + 128 + tid] += mean; }
        else {
            t->zs[tid]       = z[b * 256 + tid] + m;
            t->zs[128 + tid] = z[b * 256 + 128 + tid] + mean;
        }
    }
    if (mode == 2) {
        __syncthreads();
        if (tid < 128) {
            float a = b1[tid];
            for (int kk = 0; kk < 256; kk++) a += t->zs[kk] * W1[kk * 128 + tid];
            t->t1[tid] = fmaxf(a, 0.0f);
        }
        __syncthreads();
        if (tid < 64) {
            float a = b2[tid];
            for (int kk = 0; kk < 128; kk++) a += t->t1[kk] * W2[kk * 64 + tid];
            t->t2[tid] = fmaxf(a, 0.0f);
        }
        __syncthreads();
        if (tid < 10) {
            float a = b3[tid];
            for (int kk = 0; kk < 64; kk++) a += t->t2[kk] * W3[kk * 10 + tid];
            t->t3[tid] = a;
        }
        __syncthreads();
        if (tid == 0) {
            float m = -INFINITY;
            for (int i = 0; i < 10; i++) m = fmaxf(m, t->t3[i]);
            float su = 0.0f;
            for (int i = 0; i < 10; i++) su += expf(t->t3[i] - m);
            float ls = logf(su);
            for (int i = 0; i < 10; i++) out[b * 10 + i] = t->t3[i] - m - ls;
        }
    }
}

// ---- grid-stride gather phase (verbatim inner chain -> bit-identical per node) ----
__device__ void gather_phase(const int* __restrict__ deg, const int* __restrict__ col,
                             const float* __restrict__ x, float* __restrict__ mean, int n) {
    for (int g = blockIdx.x * 1024 + threadIdx.x; g < n * 32; g += GRIDN * 1024) {
        int node = g >> 5, sub = g & 31;
        int d = deg[node]; if (d > CAP) d = CAP;
        const int* cp = col + (long long)node * CAP;
        float ax = 0.0f, ay = 0.0f, az = 0.0f, aw = 0.0f;
        int j = 0;
        for (; j + 8 <= d; j += 8) {
            float4 v0 = ((const float4*)(x + (long long)cp[j]     * FD))[sub];
            float4 v1 = ((const float4*)(x + (long long)cp[j + 1] * FD))[sub];
            float4 v2 = ((const float4*)(x + (long long)cp[j + 2] * FD))[sub];
            float4 v3 = ((const float4*)(x + (long long)cp[j + 3] * FD))[sub];
            float4 v4 = ((const float4*)(x + (long long)cp[j + 4] * FD))[sub];
            float4 v5 = ((const float4*)(x + (long long)cp[j + 5] * FD))[sub];
            float4 v6 = ((const float4*)(x + (long long)cp[j + 6] * FD))[sub];
            float4 v7 = ((const float4*)(x + (long long)cp[j + 7] * FD))[sub];
            ax += v0.x; ay += v0.y; az += v0.z; aw += v0.w;
            ax += v1.x; ay += v1.y; az += v1.z; aw += v1.w;
            ax += v2.x; ay += v2.y; az += v2.z; aw += v2.w;
            ax += v3.x; ay += v3.y; az += v3.z; aw += v3.w;
            ax += v4.x; ay += v4.y; az += v4.z; aw += v4.w;
            ax += v5.x; ay += v5.y; az += v5.z; aw += v5.w;
            ax += v6.x; ay += v6.y; az += v6.z; aw += v6.w;
            ax += v7.x; ay += v7.y; az += v7.z; aw += v7.w;
        }
        for (; j + 4 <= d; j += 4) {
            float4 v0 = ((const float4*)(x + (long long)cp[j]     * FD))[sub];
            float4 v1 = ((const float4*)(x + (long long)cp[j + 1] * FD))[sub];
            float4 v2 = ((const float4*)(x + (long long)cp[j + 2] * FD))[sub];
            float4 v3 = ((const float4*)(x + (long long)cp[j + 3] * FD))[sub];
            ax += v0.x; ay += v0.y; az += v0.z; aw += v0.w;
            ax += v1.x; ay += v1.y; az += v1.z; aw += v1.w;
            ax += v2.x; ay += v2.y; az += v2.z; aw += v2.w;
            ax += v3.x; ay += v3.y; az += v3.z; aw += v3.w;
        }
        for (; j < d; ++j) {
            float4 v = ((const float4*)(x + (long long)cp[j] * FD))[sub];
            ax += v.x; ay += v.y; az += v.z; aw += v.w;
        }
        float inv = 1.0f / fmaxf((float)d, 1.0f);
        float4 o; o.x = ax * inv; o.y = ay * inv; o.z = az * inv; o.w = aw * inv;
        ((float4*)(mean + (long long)node * FD))[sub] = o;
    }
}

// ---- gemm phase: 256-row tile, 16 waves, dbuf B staging (same math/order as R9) ----
__device__ void gemm_phase(ChainSM* sm,
        const float* __restrict__ mean, const float* __restrict__ x,
        const unsigned short* __restrict__ wt_hi, const unsigned short* __restrict__ wt_lo,
        const float* __restrict__ bl, const float* __restrict__ pw,
        float* __restrict__ hout, float* __restrict__ score, int M) {
    GemmSM* g = &sm->g;
    int tid  = threadIdx.x;
    int wave = tid >> 6, lane = tid & 63;
    int quad = lane >> 4, l15 = lane & 15;
    int row0 = blockIdx.x * 256;

    v4f acc[8];
#pragma unroll
    for (int t = 0; t < 8; t++) acc[t] = (v4f){0.f, 0.f, 0.f, 0.f};

    if (tid < 16) {
        float s = 0.f;
#pragma unroll
        for (int t = 0; t < 8; t++) { float p = pw[t * 16 + tid]; s += p * p; }
        g->snrmp[tid] = s;
    }

    int growA = row0 + 16 * wave + l15; if (growA > M - 1) growA = M - 1;

    uint4 gh, gl;
    if (tid < 512) {
        gh = ((const uint4*)(wt_hi))[tid];
        gl = ((const uint4*)(wt_lo))[tid];
    }
    const float* ap0 = mean + (long long)growA * FD + quad * 8;
    float4 av0 = *(const float4*)(ap0);
    float4 av1 = *(const float4*)(ap0 + 4);
    if (tid < 512) {
        *(uint4*)&g->Bh[0][tid * 8] = gh;
        *(uint4*)&g->Bl[0][tid * 8] = gl;
    }

    for (int kt = 0; kt < 8; ++kt) {
        int cur = kt & 1;
        float f[8] = {av0.x, av0.y, av0.z, av0.w, av1.x, av1.y, av1.z, av1.w};
        v8s a_h, a_l;
#pragma unroll
        for (int q = 0; q < 8; q++) {
            unsigned short hb = f2bf(f[q]);
            a_h[q] = (short)hb;
            a_l[q] = (short)f2bf(f[q] - bf2f(hb));
        }
        if (kt < 7) {
            if (tid < 512) {
                gh = ((const uint4*)(wt_hi + (kt + 1) * 4096))[tid];
                gl = ((const uint4*)(wt_lo + (kt + 1) * 4096))[tid];
            }
            const float* Ab = (kt + 1 < 4) ? mean : x;
            const float* apn = Ab + (long long)growA * FD
                             + ((kt + 1 < 4) ? (kt + 1) : (kt - 3)) * 32 + quad * 8;
            av0 = *(const float4*)(apn);
            av1 = *(const float4*)(apn + 4);
        }
        __syncthreads();
#pragma unroll
        for (int t = 0; t < 8; t++) {
            v8s b_h = *(const v8s*)&g->Bh[cur][t * 512 + lane * 8];
            v8s b_l = *(const v8s*)&g->Bl[cur][t * 512 + lane * 8];
            acc[t] = __builtin_amdgcn_mfma_f32_16x16x32_bf16(a_l, b_h, acc[t], 0, 0, 0);
            acc[t] = __builtin_amdgcn_mfma_f32_16x16x32_bf16(a_h, b_l, acc[t], 0, 0, 0);
            acc[t] = __builtin_amdgcn_mfma_f32_16x16x32_bf16(a_h, b_h, acc[t], 0, 0, 0);
        }
        if (kt < 7 && tid < 512) {
            *(uint4*)&g->Bh[cur ^ 1][tid * 8] = gh;
            *(uint4*)&g->Bl[cur ^ 1][tid * 8] = gl;
        }
    }

    int rbase = row0 + 16 * wave + quad * 4;
    float part[4] = {0.f, 0.f, 0.f, 0.f};
#pragma unroll
    for (int t = 0; t < 8; t++) {
        int colc = t * 16 + l15;
        float blv = bl[colc];
        float pwv = pw[colc];
#pragma unroll
        for (int reg = 0; reg < 4; reg++) {
            float h = fmaxf(acc[t][reg] + blv, 0.0f);
            part[reg] += h * pwv;
            int grow = rbase + reg;
            if (grow < M) hout[(long long)grow * FD + colc] = h;
        }
    }
#pragma unroll
    for (int reg = 0; reg < 4; reg++)
        g->spart[(16 * wave + quad * 4 + reg) * 16 + l15] = part[reg];
    __syncthreads();
    if (tid < 256) {
        int grow = row0 + tid;
        if (grow < M) {
            float dot = 0.0f;
#pragma unroll
            for (int i = 0; i < 16; i++) dot += g->spart[tid * 16 + i];
            float nr = 0.0f;
#pragma unroll
            for (int i = 0; i < 16; i++) nr += g->snrmp[i];
            score[grow] = tanhf(dot / sqrtf(nr));
        }
    }
}

__global__ __launch_bounds__(1024) void tail_chain_kernel(
        float* __restrict__ scbuf, float* __restrict__ hout,
        const int* __restrict__ ei, float* __restrict__ xp,
        int* __restrict__ gmap, int* __restrict__ deg, int* __restrict__ colb,
        float* __restrict__ mean, float* __restrict__ z,
        const unsigned short* __restrict__ wt_hi, const unsigned short* __restrict__ wt_lo,
        const float* __restrict__ bl2, const float* __restrict__ pw2,
        const float* __restrict__ bl3, const float* __restrict__ pw3,
        const float* __restrict__ W1, const float* __restrict__ b1,
        const float* __restrict__ W2, const float* __restrict__ b2,
        const float* __restrict__ W3, const float* __restrict__ b3,
        float* __restrict__ out, unsigned* __restrict__ bar) {
    __shared__ ChainSM sm;
    const int N2 = BG * K1, N3 = BG * K2;

    // T1: sort + layer2 CSR + gmap + pool -> xp + readout(z, mode 0)
    tail_phase(&sm, scbuf, hout, NPG, K1, 512, xp, ei, ei + EE, gmap,
               deg, colb, z, 0, W1, b1, W2, b2, W3, b3, out);
    grid_sync(bar, GRIDN);

    // G2
    gather_phase(deg, colb, xp, mean, N2);
    grid_sync(bar, GRIDN);

    // M2
    if ((int)blockIdx.x < (N2 + 255) / 256)
        gemm_phase(&sm, mean, xp, wt_hi + 32768, wt_lo + 32768, bl2, pw2, hout, scbuf, N2);
    grid_sync(bar, GRIDN);

    // T2
    tail_phase(&sm, scbuf, hout, K1, K2, 256, xp, ei, ei + EE, gmap,
               deg, colb, z, 1, W1, b1, W2, b2, W3, b3, out);
    grid_sync(bar, GRIDN);

    // G3
    gather_phase(deg, colb, xp, mean, N3);
    grid_sync(bar, GRIDN);

    // M3
    if ((int)blockIdx.x < (N3 + 255) / 256)
        gemm_phase(&sm, mean, xp, wt_hi + 65536, wt_lo + 65536, bl3, pw3, hout, scbuf, N3);
    grid_sync(bar, GRIDN);

    // T3: final sort + pool + MLP -> out
    tail_phase(&sm, scbuf, hout, K2, K3, 128, xp, (const int*)0, (const int*)0, gmap,
               deg, colb, z, 2, W1, b1, W2, b2, W3, b3, out);
}

extern "C" void kernel_launch(void* const* d_in, const int* in_sizes, int n_in,
                              void* d_out, int out_size, void* d_ws, size_t ws_size,
                              hipStream_t stream) {
    (void)in_sizes; (void)n_in; (void)out_size; (void)ws_size;
    const float* x   = (const float*)d_in[0];
    const int*   ei  = (const int*)d_in[1];
    const float* Wl1 = (const float*)d_in[2];
    const float* bl1 = (const float*)d_in[3];
    const float* Wr1 = (const float*)d_in[4];
    const float* Wl2 = (const float*)d_in[5];
    const float* bl2 = (const float*)d_in[6];
    const float* Wr2 = (const float*)d_in[7];
    const float* Wl3 = (const float*)d_in[8];
    const float* bl3 = (const float*)d_in[9];
    const float* Wr3 = (const float*)d_in[10];
    const float* pw1 = (const float*)d_in[11];
    const float* pw2 = (const float*)d_in[12];
    const float* pw3 = (const float*)d_in[13];
    const float* W1  = (const float*)d_in[14];
    const float* b1  = (const float*)d_in[15];
    const float* W2  = (const float*)d_in[16];
    const float* b2  = (const float*)d_in[17];
    const float* W3  = (const float*)d_in[18];
    const float* b3  = (const float*)d_in[19];
    float* out = (float*)d_out;

    // workspace layout
    char* ws = (char*)d_ws;
    size_t off = 0;
    auto alloc = [&](size_t bytes) {
        char* p = ws + off;
        off = (off + bytes + 255) & ~(size_t)255;
        return p;
    };
    float* mean  = (float*)alloc((size_t)NN * FD * 4);
    float* hout  = (float*)alloc((size_t)NN * FD * 4);
    float* xp    = (float*)alloc((size_t)BG * K1 * FD * 4);
    float* sc    = (float*)alloc((size_t)NN * 4);
    int*   gmap  = (int*)  alloc((size_t)NN * 4);
    int*   deg   = (int*)  alloc((size_t)NN * 4);
    int*   colb  = (int*)  alloc((size_t)NN * CAP * 4);   // 12.8 MB
    float* z     = (float*)alloc((size_t)BG * 256 * 4);
    unsigned short* wt_hi = (unsigned short*)alloc((size_t)3 * 32768 * 2);
    unsigned short* wt_lo = (unsigned short*)alloc((size_t)3 * 32768 * 2);
    unsigned* bar = (unsigned*)alloc(256);

    // ================= prep (CSR build + W conversion + barrier reset) =================
    prep_fill_kernel<<<BG + 96, 1024, 0, stream>>>(ei, deg, colb,
                                                   Wl1, Wr1, Wl2, Wr2, Wl3, Wr3,
                                                   wt_hi, wt_lo, bar);

    // ================= layer 1 (device-wide TLP kernels) =================
    {
        int nb = (NN * 32 + 255) / 256;
        gather_agg_kernel<<<nb, 256, 0, stream>>>(deg, colb, x, mean, NN, nb);
    }
    {
        int nb = (NN + 127) / 128;
        sage_gemm_mfma_kernel<<<nb, 512, 0, stream>>>(mean, x, wt_hi, wt_lo,
                                                      bl1, pw1, hout, sc, NN, nb);
    }

    // ================= tail chain: one kernel, grid barriers =================
    tail_chain_kernel<<<GRIDN, 1024, 0, stream>>>(sc, hout, ei, xp, gmap, deg, colb,
                                                  mean, z, wt_hi, wt_lo,
                                                  bl2, pw2, bl3, pw3,
                                                  W1, b1, W2, b2, W3, b3, out, bar);
}

// Round 11
// 238.115 us; speedup vs baseline: 4.6537x; 4.6537x over previous
//
#include <hip/hip_runtime.h>
#include <math.h>

// Problem constants (from reference)
#define BG    100        // graphs
#define NPG   500        // nodes per graph (layer 1)
#define FD    128        // feature dim (F_IN == H == 128)
#define EE    600000     // edges
#define EPG   6000       // edges per graph (contiguous, never cross graphs)
#define NN    50000      // total nodes layer 1
#define K1    250
#define K2    125
#define K3    63
#define CAP   64         // max in-degree capacity

typedef short v8s __attribute__((ext_vector_type(8)));
typedef float v4f __attribute__((ext_vector_type(4)));

// XCD-aligned swizzle (R9 win)
__device__ __forceinline__ int swz(int p, int N) {
    int j = p & 7, i = p >> 3;
    int chunk = N >> 3, rem = N & 7;
    int mj = j < rem ? j : rem;
    return j * chunk + mj + i;
}

// float -> bf16 RNE bits
__device__ __forceinline__ unsigned short f2bf(float f) {
    unsigned int u = __float_as_uint(f);
    unsigned int r = (u + 0x7FFFu + ((u >> 16) & 1u)) >> 16;
    return (unsigned short)r;
}
__device__ __forceinline__ float bf2f(unsigned short b) {
    return __uint_as_float(((unsigned int)b) << 16);
}

// ---------------- merged prep: blocks [0,BG) build layer-1 CSR (LDS counters);
// blocks [BG, BG+96) convert W -> Wt_hi/Wt_lo bf16 in MFMA-staging order:
// o = [layer][kt=k>>5][t=n>>4][quad=(k>>3)&3][l15=n&15][q=k&7]  (k = [Wl | Wr] rows)
__global__ __launch_bounds__(1024) void prep_fill_kernel(
        const int* __restrict__ ei, int* __restrict__ deg, int* __restrict__ col,
        const float* __restrict__ Wl1, const float* __restrict__ Wr1,
        const float* __restrict__ Wl2, const float* __restrict__ Wr2,
        const float* __restrict__ Wl3, const float* __restrict__ Wr3,
        unsigned short* __restrict__ wt_hi, unsigned short* __restrict__ wt_lo) {
    __shared__ int lcnt[NPG];
    int tid = threadIdx.x;
    if (blockIdx.x < BG) {
        int b = swz(blockIdx.x, BG);
        for (int i = tid; i < NPG; i += 1024) lcnt[i] = 0;
        __syncthreads();
        for (int e0 = tid; e0 < EPG; e0 += 1024) {
            int e = b * EPG + e0;
            int d = ei[EE + e];
            int pos = atomicAdd(&lcnt[d - b * NPG], 1);
            if (pos < CAP) col[(long long)d * CAP + pos] = ei[e];
        }
        __syncthreads();
        for (int i = tid; i < NPG; i += 1024) deg[b * NPG + i] = lcnt[i];
    } else {
        int id = (blockIdx.x - BG) * 1024 + tid;          // 3*256*128 = 98304
        if (id >= 3 * 256 * 128) return;
        int layer = id >> 15, rem = id & 32767;
        int k = rem >> 7, n = rem & 127;
        const float* Wl = layer == 0 ? Wl1 : (layer == 1 ? Wl2 : Wl3);
        const float* Wr = layer == 0 ? Wr1 : (layer == 1 ? Wr2 : Wr3);
        float w = (k < 128) ? Wl[k * 128 + n] : Wr[(k - 128) * 128 + n];
        unsigned short hi = f2bf(w);
        unsigned short lo = f2bf(w - bf2f(hi));
        long long o = (long long)layer * 32768
                    + (long long)(k >> 5) * 4096          // kt
                    + (long long)(n >> 4) * 512           // t
                    + (long long)((k >> 3) & 3) * 128     // quad
                    + (long long)(n & 15) * 8             // l15
                    + (k & 7);                            // q
        wt_hi[o] = hi;
        wt_lo[o] = lo;
    }
}

// ---------------- gather-aggregate (coalesced, high TLP, 8-way pipelined) ----------------
__global__ void gather_agg_kernel(const int* __restrict__ deg, const int* __restrict__ col,
                                  const float* __restrict__ x, float* __restrict__ mean,
                                  int n, int NB) {
    int g = swz(blockIdx.x, NB) * 256 + threadIdx.x;
    int node = g >> 5, sub = g & 31;
    if (node >= n) return;
    int d = deg[node]; if (d > CAP) d = CAP;
    const int* cp = col + (long long)node * CAP;
    float ax = 0.0f, ay = 0.0f, az = 0.0f, aw = 0.0f;
    int j = 0;
    for (; j + 8 <= d; j += 8) {
        float4 v0 = ((const float4*)(x + (long long)cp[j]     * FD))[sub];
        float4 v1 = ((const float4*)(x + (long long)cp[j + 1] * FD))[sub];
        float4 v2 = ((const float4*)(x + (long long)cp[j + 2] * FD))[sub];
        float4 v3 = ((const float4*)(x + (long long)cp[j + 3] * FD))[sub];
        float4 v4 = ((const float4*)(x + (long long)cp[j + 4] * FD))[sub];
        float4 v5 = ((const float4*)(x + (long long)cp[j + 5] * FD))[sub];
        float4 v6 = ((const float4*)(x + (long long)cp[j + 6] * FD))[sub];
        float4 v7 = ((const float4*)(x + (long long)cp[j + 7] * FD))[sub];
        ax += v0.x; ay += v0.y; az += v0.z; aw += v0.w;
        ax += v1.x; ay += v1.y; az += v1.z; aw += v1.w;
        ax += v2.x; ay += v2.y; az += v2.z; aw += v2.w;
        ax += v3.x; ay += v3.y; az += v3.z; aw += v3.w;
        ax += v4.x; ay += v4.y; az += v4.z; aw += v4.w;
        ax += v5.x; ay += v5.y; az += v5.z; aw += v5.w;
        ax += v6.x; ay += v6.y; az += v6.z; aw += v6.w;
        ax += v7.x; ay += v7.y; az += v7.z; aw += v7.w;
    }
    for (; j + 4 <= d; j += 4) {
        float4 v0 = ((const float4*)(x + (long long)cp[j]     * FD))[sub];
        float4 v1 = ((const float4*)(x + (long long)cp[j + 1] * FD))[sub];
        float4 v2 = ((const float4*)(x + (long long)cp[j + 2] * FD))[sub];
        float4 v3 = ((const float4*)(x + (long long)cp[j + 3] * FD))[sub];
        ax += v0.x; ay += v0.y; az += v0.z; aw += v0.w;
        ax += v1.x; ay += v1.y; az += v1.z; aw += v1.w;
        ax += v2.x; ay += v2.y; az += v2.z; aw += v2.w;
        ax += v3.x; ay += v3.y; az += v3.z; aw += v3.w;
    }
    for (; j < d; ++j) {
        float4 v = ((const float4*)(x + (long long)cp[j] * FD))[sub];
        ax += v.x; ay += v.y; az += v.z; aw += v.w;
    }
    float inv = 1.0f / fmaxf((float)d, 1.0f);
    float4 o; o.x = ax * inv; o.y = ay * inv; o.z = az * inv; o.w = aw * inv;
    ((float4*)(mean + (long long)node * FD))[sub] = o;
}

// ---------------- SAGE GEMM (128-row tile, 8 waves, double-buffered B staging) --------
// h = relu([mean|x]@[Wl;Wr] + bl), score = tanh(h.pw/||pw||).
// K-loop pipeline: stage kt into LDS[kt&1]; during MFMA of kt, prefetch kt+1 (B slab
// + A fragment) into registers; write them to LDS[(kt+1)&1] AFTER the barrier (no
// reader until the next barrier -> WAR-safe). ONE barrier per kt (was 2) and global
// load latency hides under MFMA+convert. Same values, same MFMA order -> bit-identical.
__global__ __launch_bounds__(512) void sage_gemm_mfma_kernel(
        const float* __restrict__ mean, const float* __restrict__ x,
        const unsigned short* __restrict__ wt_hi, const unsigned short* __restrict__ wt_lo,
        const float* __restrict__ bl, const float* __restrict__ pw,
        float* __restrict__ hout, float* __restrict__ score, int M, int NB) {
    __shared__ unsigned short Bh[2][4096], Bl[2][4096];   // kt-slab: [t][quad][l15][q]
    __shared__ float spart[128 * 16];
    __shared__ float snrmp[16];
    int tid  = threadIdx.x;
    int wave = tid >> 6, lane = tid & 63;
    int quad = lane >> 4, l15 = lane & 15;
    int row0 = swz(blockIdx.x, NB) * 128;

    v4f acc[8];
#pragma unroll
    for (int t = 0; t < 8; t++) acc[t] = (v4f){0.f, 0.f, 0.f, 0.f};

    if (tid < 16) {
        float s = 0.f;
#pragma unroll
        for (int t = 0; t < 8; t++) { float p = pw[t * 16 + tid]; s += p * p; }
        snrmp[tid] = s;
    }

    int growA = row0 + 16 * wave + l15; if (growA > M - 1) growA = M - 1;

    // ---- prologue: prefetch kt=0 and stage into LDS[0] ----
    uint4 gh = ((const uint4*)(wt_hi))[tid];
    uint4 gl = ((const uint4*)(wt_lo))[tid];
    const float* ap0 = mean + (long long)growA * FD + quad * 8;   // kt=0: mean, koff 0
    float4 av0 = *(const float4*)(ap0);
    float4 av1 = *(const float4*)(ap0 + 4);
    *(uint4*)&Bh[0][tid * 8] = gh;
    *(uint4*)&Bl[0][tid * 8] = gl;

    for (int kt = 0; kt < 8; ++kt) {
        int cur = kt & 1;
        // ---- convert current A to hi/lo in registers ----
        float f[8] = {av0.x, av0.y, av0.z, av0.w, av1.x, av1.y, av1.z, av1.w};
        v8s a_h, a_l;
#pragma unroll
        for (int q = 0; q < 8; q++) {
            unsigned short hb = f2bf(f[q]);
            a_h[q] = (short)hb;
            a_l[q] = (short)f2bf(f[q] - bf2f(hb));
        }
        // ---- issue prefetch for kt+1 (B slab + A fragment) ----
        if (kt < 7) {
            gh = ((const uint4*)(wt_hi + (kt + 1) * 4096))[tid];
            gl = ((const uint4*)(wt_lo + (kt + 1) * 4096))[tid];
            const float* Ab = (kt + 1 < 4) ? mean : x;
            const float* apn = Ab + (long long)growA * FD
                             + ((kt + 1 < 4) ? (kt + 1) : (kt - 3)) * 32 + quad * 8;
            av0 = *(const float4*)(apn);
            av1 = *(const float4*)(apn + 4);
        }
        __syncthreads();   // LDS[cur] fully staged by all threads
        // ---- MFMA over the 8 column tiles (conflict-free lane-contiguous reads) ----
#pragma unroll
        for (int t = 0; t < 8; t++) {
            v8s b_h = *(const v8s*)&Bh[cur][t * 512 + lane * 8];
            v8s b_l = *(const v8s*)&Bl[cur][t * 512 + lane * 8];
            acc[t] = __builtin_amdgcn_mfma_f32_16x16x32_bf16(a_l, b_h, acc[t], 0, 0, 0);
            acc[t] = __builtin_amdgcn_mfma_f32_16x16x32_bf16(a_h, b_l, acc[t], 0, 0, 0);
            acc[t] = __builtin_amdgcn_mfma_f32_16x16x32_bf16(a_h, b_h, acc[t], 0, 0, 0);
        }
        // ---- stage kt+1 into the other buffer (no reader until next barrier) ----
        if (kt < 7) {
            *(uint4*)&Bh[cur ^ 1][tid * 8] = gh;
            *(uint4*)&Bl[cur ^ 1][tid * 8] = gl;
        }
    }

    // ---- epilogue: bias + relu + store h + score partials ----
    int rbase = row0 + 16 * wave + quad * 4;
    float part[4] = {0.f, 0.f, 0.f, 0.f};
#pragma unroll
    for (int t = 0; t < 8; t++) {
        int colc = t * 16 + l15;
        float blv = bl[colc];
        float pwv = pw[colc];
#pragma unroll
        for (int reg = 0; reg < 4; reg++) {
            float h = fmaxf(acc[t][reg] + blv, 0.0f);
            part[reg] += h * pwv;
            int grow = rbase + reg;
            if (grow < M) hout[(long long)grow * FD + colc] = h;
        }
    }
#pragma unroll
    for (int reg = 0; reg < 4; reg++)
        spart[(16 * wave + quad * 4 + reg) * 16 + l15] = part[reg];
    __syncthreads();
    if (tid < 128) {
        int grow = row0 + tid;
        if (grow < M) {
            float dot = 0.0f;
#pragma unroll
            for (int i = 0; i < 16; i++) dot += spart[tid * 16 + i];
            float nr = 0.0f;
#pragma unroll
            for (int i = 0; i < 16; i++) nr += snrmp[i];
            score[grow] = tanhf(dot / sqrtf(nr));
        }
    }
}

// ---------------- per-graph tail, phase-split across 2 blocks/graph ----------------
// Both blocks of a graph run the (cheap, register-resident) bitonic sort; then:
//   kind 0: edge remap + next-layer CSR + deg (+ gmap init at layer 1)
//   kind 1: pool -> xp, readout -> z (+ final MLP in mode 2)
// Edge liveness across layers via composed node map gmap[original id] -> current
// level id or -1 (identical alive-set to the reference's emask composition).
__global__ __launch_bounds__(1024) void topk_tail_kernel(
        const float* __restrict__ score, const float* __restrict__ hout,
        int n_per, int k, int SN,
        float* __restrict__ xp,
        const int* __restrict__ esrc, const int* __restrict__ edst,
        int* __restrict__ gmap,
        int* __restrict__ next_deg, int* __restrict__ next_col,
        float* __restrict__ z, int mode,
        const float* __restrict__ W1, const float* __restrict__ b1,
        const float* __restrict__ W2, const float* __restrict__ b2,
        const float* __restrict__ W3, const float* __restrict__ b3,
        float* __restrict__ out) {
    __shared__ float skey[512];
    __shared__ int   sidx[512];
    __shared__ unsigned long long spk[512];
    __shared__ int   lmap[512];
    __shared__ int   lcnt[512];
    __shared__ float pmax[1024];
    __shared__ float psum[1024];
    __shared__ float zs[256], t1[128], t2[64], t3[16];
    int tid = threadIdx.x;
    int kind, b;
    if (mode == 2) { kind = 1; b = swz(blockIdx.x, BG); }
    else {
        kind = blockIdx.x >= BG ? 1 : 0;
        b = swz(kind ? blockIdx.x - BG : blockIdx.x, BG);
    }

    if (kind == 0)
        for (int i = tid; i < SN; i += 1024) { lmap[i] = -1; lcnt[i] = 0; }

    // ---- register bitonic sort on packed keys (desc key, asc idx) ----
    unsigned long long P = 0ULL;
    if (tid < SN) {
        float keyv; unsigned int idx;
        if (tid < n_per) { keyv = score[b * n_per + tid]; idx = (unsigned int)tid; }
        else             { keyv = -INFINITY;              idx = 0x7fffffffu; }
        unsigned int u = __float_as_uint(keyv);
        u = (u & 0x80000000u) ? ~u : (u | 0x80000000u);
        P = ((unsigned long long)u << 32) | (unsigned long long)(~idx);
    }
    for (int ks = 2; ks <= SN; ks <<= 1) {
        for (int j = ks >> 1; j > 0; j >>= 1) {
            unsigned long long Q;
            if (j >= 64) {
                __syncthreads();
                if (tid < SN) spk[tid] = P;
                __syncthreads();
                Q = (tid < SN) ? spk[tid ^ j] : 0ULL;
            } else {
                Q = __shfl_xor(P, j, 64);
            }
            if (tid < SN) {
                bool keepmax = (((tid & ks) == 0) == ((tid & j) == 0));
                if (keepmax == (Q > P)) P = Q;
            }
        }
    }
    if (tid < SN) {
        unsigned int u  = (unsigned int)(P >> 32);
        unsigned int fb = (u & 0x80000000u) ? (u & 0x7fffffffu) : ~u;
        int iv = (int)(~(unsigned int)P);
        skey[tid] = __uint_as_float(fb);
        sidx[tid] = iv;
        if (kind == 0 && tid < k) lmap[iv] = tid;
    }
    __syncthreads();

    if (kind == 0) {
        // ---- edge remap + CSR build for next layer ----
        int kbase = b * k;
        if (mode == 0) {
            int nbase = b * n_per;      // n_per == NPG, original ids
            for (int e0 = tid; e0 < EPG; e0 += 1024) {
                int e = b * EPG + e0;
                int ls = lmap[esrc[e] - nbase];
                int ld = lmap[edst[e] - nbase];
                if (ls >= 0 && ld >= 0) {
                    int pos = atomicAdd(&lcnt[ld], 1);
                    if (pos < CAP) next_col[(long long)(kbase + ld) * CAP + pos] = kbase + ls;
                }
            }
            __syncthreads();
            // gmap: original node -> level-1 global id (or -1)
            for (int i = tid; i < NPG; i += 1024) {
                int l = lmap[i];
                gmap[nbase + i] = l >= 0 ? kbase + l : -1;
            }
        } else {
            // mode 1: original edges composed through gmap (level-1 ids), then lmap
            int kb1 = b * n_per;        // n_per == K1, level-1 global base
            for (int e0 = tid; e0 < EPG; e0 += 1024) {
                int e = b * EPG + e0;
                int ws = gmap[esrc[e]];
                int wd = gmap[edst[e]];
                int ls = (ws >= 0) ? lmap[ws - kb1] : -1;
                int ld = (wd >= 0) ? lmap[wd - kb1] : -1;
                if (ls >= 0 && ld >= 0) {
                    int pos = atomicAdd(&lcnt[ld], 1);
                    if (pos < CAP) next_col[(long long)(kbase + ld) * CAP + pos] = kbase + ls;
                }
            }
            __syncthreads();
        }
        for (int i = tid; i < k; i += 1024) next_deg[kbase + i] = lcnt[i];
        return;
    }

    // ---- kind 1: pool -> xp, readout ----
    int c = tid & 127, s = tid >> 7;
    float mx = -INFINITY, sm = 0.0f;
    {
        int r = s;
        long long hbase = (long long)b * n_per * FD + c;
        long long xbase = (long long)b * k * FD + c;
        for (; r + 24 < k; r += 32) {
            int i0 = sidx[r], i1 = sidx[r + 8], i2 = sidx[r + 16], i3 = sidx[r + 24];
            float k0 = skey[r], k1 = skey[r + 8], k2 = skey[r + 16], k3 = skey[r + 24];
            float v0 = hout[hbase + (long long)i0 * FD] * k0;
            float v1 = hout[hbase + (long long)i1 * FD] * k1;
            float v2 = hout[hbase + (long long)i2 * FD] * k2;
            float v3 = hout[hbase + (long long)i3 * FD] * k3;
            if (mode != 2) {
                xp[xbase + (long long)(r)      * FD] = v0;
                xp[xbase + (long long)(r + 8)  * FD] = v1;
                xp[xbase + (long long)(r + 16) * FD] = v2;
                xp[xbase + (long long)(r + 24) * FD] = v3;
            }
            mx = fmaxf(mx, v0); sm += v0;
            mx = fmaxf(mx, v1); sm += v1;
            mx = fmaxf(mx, v2); sm += v2;
            mx = fmaxf(mx, v3); sm += v3;
        }
        for (; r < k; r += 8) {
            float v = hout[hbase + (long long)sidx[r] * FD] * skey[r];
            if (mode != 2) xp[xbase + (long long)r * FD] = v;
            mx = fmaxf(mx, v); sm += v;
        }
    }
    pmax[tid] = mx; psum[tid] = sm;
    __syncthreads();
    if (tid < 128) {
        float m = -INFINITY, su = 0.0f;
#pragma unroll
        for (int i = 0; i < 8; i++) {
            m = fmaxf(m, pmax[i * 128 + tid]);
            su += psum[i * 128 + tid];
        }
        float mean = su / (float)k;
        if (mode == 0)      { z[b * 256 + tid] = m;  z[b * 256 + 128 + tid] = mean;  }
        else if (mode == 1) { z[b * 256 + tid] += m; z[b * 256 + 128 + tid] += mean; }
        else {
            zs[tid]       = z[b * 256 + tid] + m;
            zs[128 + tid] = z[b * 256 + 128 + tid] + mean;
        }
    }
    if (mode == 2) {
        __syncthreads();
        if (tid < 128) {
            float a = b1[tid];
            for (int kk = 0; kk < 256; kk++) a += zs[kk] * W1[kk * 128 + tid];
            t1[tid] = fmaxf(a, 0.0f);
        }
        __syncthreads();
        if (tid < 64) {
            float a = b2[tid];
            for (int kk = 0; kk < 128; kk++) a += t1[kk] * W2[kk * 64 + tid];
            t2[tid] = fmaxf(a, 0.0f);
        }
        __syncthreads();
        if (tid < 10) {
            float a = b3[tid];
            for (int kk = 0; kk < 64; kk++) a += t2[kk] * W3[kk * 10 + tid];
            t3[tid] = a;
        }
        __syncthreads();
        if (tid == 0) {
            float m = -INFINITY;
            for (int i = 0; i < 10; i++) m = fmaxf(m, t3[i]);
            float su = 0.0f;
            for (int i = 0; i < 10; i++) su += expf(t3[i] - m);
            float ls = logf(su);
            for (int i = 0; i < 10; i++) out[b * 10 + i] = t3[i] - m - ls;
        }
    }
}

extern "C" void kernel_launch(void* const* d_in, const int* in_sizes, int n_in,
                              void* d_out, int out_size, void* d_ws, size_t ws_size,
                              hipStream_t stream) {
    (void)in_sizes; (void)n_in; (void)out_size; (void)ws_size;
    const float* x   = (const float*)d_in[0];
    const int*   ei  = (const int*)d_in[1];
    const float* Wl1 = (const float*)d_in[2];
    const float* bl1 = (const float*)d_in[3];
    const float* Wr1 = (const float*)d_in[4];
    const float* Wl2 = (const float*)d_in[5];
    const float* bl2 = (const float*)d_in[6];
    const float* Wr2 = (const float*)d_in[7];
    const float* Wl3 = (const float*)d_in[8];
    const float* bl3 = (const float*)d_in[9];
    const float* Wr3 = (const float*)d_in[10];
    const float* pw1 = (const float*)d_in[11];
    const float* pw2 = (const float*)d_in[12];
    const float* pw3 = (const float*)d_in[13];
    const float* W1  = (const float*)d_in[14];
    const float* b1  = (const float*)d_in[15];
    const float* W2  = (const float*)d_in[16];
    const float* b2  = (const float*)d_in[17];
    const float* W3  = (const float*)d_in[18];
    const float* b3  = (const float*)d_in[19];
    float* out = (float*)d_out;

    // workspace layout
    char* ws = (char*)d_ws;
    size_t off = 0;
    auto alloc = [&](size_t bytes) {
        char* p = ws + off;
        off = (off + bytes + 255) & ~(size_t)255;
        return p;
    };
    float* mean  = (float*)alloc((size_t)NN * FD * 4);
    float* hout  = (float*)alloc((size_t)NN * FD * 4);
    float* xp    = (float*)alloc((size_t)BG * K1 * FD * 4);
    float* sc    = (float*)alloc((size_t)NN * 4);
    int*   gmap  = (int*)  alloc((size_t)NN * 4);
    int*   deg   = (int*)  alloc((size_t)NN * 4);
    int*   colb  = (int*)  alloc((size_t)NN * CAP * 4);   // 12.8 MB
    float* z     = (float*)alloc((size_t)BG * 256 * 4);
    unsigned short* wt_hi = (unsigned short*)alloc((size_t)3 * 32768 * 2);
    unsigned short* wt_lo = (unsigned short*)alloc((size_t)3 * 32768 * 2);

    // ================= prep (CSR build + W conversion, one launch) =================
    prep_fill_kernel<<<BG + 96, 1024, 0, stream>>>(ei, deg, colb,
                                                   Wl1, Wr1, Wl2, Wr2, Wl3, Wr3, wt_hi, wt_lo);

    // ================= layer 1 =================
    {
        int nb = (NN * 32 + 255) / 256;
        gather_agg_kernel<<<nb, 256, 0, stream>>>(deg, colb, x, mean, NN, nb);
    }
    {
        int nb = (NN + 127) / 128;
        sage_gemm_mfma_kernel<<<nb, 512, 0, stream>>>(mean, x, wt_hi, wt_lo,
                                                      bl1, pw1, hout, sc, NN, nb);
    }
    topk_tail_kernel<<<2 * BG, 1024, 0, stream>>>(sc, hout, NPG, K1, 512, xp,
                                                  ei, ei + EE, gmap, deg, colb,
                                                  z, 0, W1, b1, W2, b2, W3, b3, out);

    // ================= layer 2 =================
    const int N2 = BG * K1;   // 25000
    {
        int nb = (N2 * 32 + 255) / 256;
        gather_agg_kernel<<<nb, 256, 0, stream>>>(deg, colb, xp, mean, N2, nb);
    }
    {
        int nb = (N2 + 127) / 128;
        sage_gemm_mfma_kernel<<<nb, 512, 0, stream>>>(mean, xp, wt_hi + 32768, wt_lo + 32768,
                                                      bl2, pw2, hout, sc, N2, nb);
    }
    topk_tail_kernel<<<2 * BG, 1024, 0, stream>>>(sc, hout, K1, K2, 256, xp,
                                                  ei, ei + EE, gmap, deg, colb,
                                                  z, 1, W1, b1, W2, b2, W3, b3, out);

    // ================= layer 3 =================
    const int N3 = BG * K2;   // 12500
    {
        int nb = (N3 * 32 + 255) / 256;
        gather_agg_kernel<<<nb, 256, 0, stream>>>(deg, colb, xp, mean, N3, nb);
    }
    {
        int nb = (N3 + 127) / 128;
        sage_gemm_mfma_kernel<<<nb, 512, 0, stream>>>(mean, xp, wt_hi + 65536, wt_lo + 65536,
                                                      bl3, pw3, hout, sc, N3, nb);
    }
    topk_tail_kernel<<<BG, 1024, 0, stream>>>(sc, hout, K2, K3, 128, (float*)0,
                                              (const int*)0, (const int*)0, (int*)0,
                                              (int*)0, (int*)0,
                                              z, 2, W1, b1, W2, b2, W3, b3, out);
}